// Round 5
// baseline (399.379 us; speedup 1.0000x reference)
//
#include <hip/hip_runtime.h>
#include <hip/hip_bf16.h>

#define B_DIM 2
#define T_DIM 320
#define L_DIM 207
#define D_DIM 64
#define S_DIM 21
#define J_TOT (S_DIM * L_DIM)   // 4347
#define MPAD 224                // m padded to 7*32
#define IPAD 256                // i padded for pp chunks
#define NSPLIT 4
#define TSPLIT 80               // 320/4
#define NCH_A 128
#define CH_A 34                 // ceil(4347/128)
#define NCH_P 128
#define CH_P 34                 // ceil(4347/128)
#define LD_ROW (L_DIM * D_DIM)  // 13248
#define SLAB_B 26496            // bytes per (b,t) slab of xbf

typedef __attribute__((ext_vector_type(8))) short bf16x8;   // 8 bf16 (4 VGPRs)
typedef __attribute__((ext_vector_type(4))) float f32x4;

__device__ inline unsigned short f2bf(float f) {
    unsigned int u = __builtin_bit_cast(unsigned int, f);
    u = (u + 0x7FFFu + ((u >> 16) & 1u)) >> 16;   // RNE
    return (unsigned short)u;
}

__device__ inline int shift_p(int s) { return (s == 0) ? 287 : (21 - s); }
__device__ inline int imin(int a, int b) { return a < b ? a : b; }
__device__ inline int imax(int a, int b) { return a > b ? a : b; }

// async 16B global->LDS (DMA). LDS dest = wave-uniform base + lane*16;
// global source is per-lane.
__device__ __forceinline__ void glds16(const void* g, void* l) {
    __builtin_amdgcn_global_load_lds(
        (const __attribute__((address_space(1))) void*)g,
        (__attribute__((address_space(3))) void*)l,
        16, 0, 0);
}

// K0: x fp32 [B,T,L,D] -> xbf bf16 [B,T,L,D] and xt bf16 [B,T][mc7][d64][mi32]
__global__ void __launch_bounds__(256) k_prep(const float* __restrict__ x,
                                              unsigned short* __restrict__ xbf,
                                              unsigned short* __restrict__ xt) {
    __shared__ float tile[L_DIM * 66];
    int bt = blockIdx.x;
    const float* src = x + (size_t)bt * LD_ROW;
    int tid = threadIdx.x;
    for (int idx = tid; idx < L_DIM * D_DIM; idx += 256) {
        int l = idx >> 6, d = idx & 63;
        tile[l * 66 + d] = src[idx];
    }
    __syncthreads();
    unsigned short* dst1 = xbf + (size_t)bt * LD_ROW;
    for (int idx = tid; idx < L_DIM * D_DIM; idx += 256) {
        int l = idx >> 6, d = idx & 63;
        dst1[idx] = f2bf(tile[l * 66 + d]);
    }
    unsigned short* dst2 = xt + (size_t)bt * (7 * 64 * 32);
    if (tid < MPAD) {
        int mc = tid >> 5, mi = tid & 31;
        for (int d = 0; d < D_DIM; ++d) {
            float v = (tid < L_DIM) ? tile[tid * 66 + d] : 0.0f;
            dst2[(mc * 64 + d) * 32 + mi] = f2bf(v);
        }
    }
}

// ---------------- K1a: logit partials for s=1..20 (register-ring) -----------
// v5: prefetch depth 3 (vmcnt(3)); A-ring 8 slabs (stage t+3 never collides
// with a skew-1 reader of (t-1)&7), B-ring 24 slabs (stage t+23 vs oldest
// live t+9: distance 14 < 24). One barrier/step. LDS 128 KB -> 1 block/CU.
__global__ void __launch_bounds__(512, 2) k_simr(const unsigned short* __restrict__ xbf,
                                                 const unsigned short* __restrict__ zpage,
                                                 float* __restrict__ part) {
    __shared__ __align__(16) unsigned short Asl[8][2048];    // 8 x 4 KB
    __shared__ __align__(16) unsigned short Bsl[24][2048];   // 24 x 4 KB

    int id = blockIdx.x;
    int split = id / 98;                 // 0..3 (t-chunk)
    int r2 = id % 98;
    int b = r2 & 1;
    int pb = r2 >> 1;                    // 0..48
    int lfb = pb / 7, mfb = pb % 7;

    int t0 = split * TSPLIT;             // 0,80,160,240 (== 0 mod 10)
    int t1 = t0 + TSPLIT;

    int tid = threadIdx.x;
    int w = tid >> 6, lane = tid & 63;
    int wl = w & 1, wm = (w >> 1) & 1, h = w >> 2;
    int fr = lane & 15, kg = lane >> 4;
    int x7 = fr & 7;

    int lf = lfb * 2 + wl;               // 0..13
    int mf = mfb * 2 + wm;
    bool wvalid = (lf <= 12) && (mf <= 12);   // frag 13 is pure pad

    // staging: waves 0-3 stage A-slab (4 KB), waves 4-7 stage B-slab.
    bool isA = (w < 4);
    int gq = (w & 3) * 64 + lane;        // 0..255 within stage group
    int grow = gq >> 3, gc = gq & 7;
    int srcoff = grow * 128 + ((gc ^ (grow & 7)) * 16);   // pre-swizzled source
    int dstoff = (w & 3) * 1024;         // wave-uniform LDS dest base

    const char* xb = (const char*)xbf;
    size_t abase = (size_t)b * T_DIM * SLAB_B + lfb * 4096;
    size_t bbase = (size_t)b * T_DIM * SLAB_B + mfb * 4096;

    // fragment read offsets (read-side XOR matches source pre-swizzle)
    int lrA = wl * 16 + fr, lrB = wm * 16 + fr;
    int c0 = ((0 + kg) ^ x7) * 16, c1 = ((4 + kg) ^ x7) * 16;
    int aoff0 = lrA * 128 + c0, aoff1 = lrA * 128 + c1;
    int boff0 = lrB * 128 + c0, boff1 = lrB * 128 + c1;

    f32x4 acc[10];
#pragma unroll
    for (int j = 0; j < 10; ++j) acc[j] = f32x4{0.f, 0.f, 0.f, 0.f};
    bf16x8 ring[10][2];                  // ALL indices compile-time (rule 20)

    // ---- prologue: stage A(t0..t0+2) + B(t0+1..t0+22), drain, preload ring
    if (isA) {
#pragma unroll
        for (int i = 0; i < 3; ++i)
            glds16(xb + abase + (size_t)(t0 + i) * SLAB_B + srcoff,
                   (char*)Asl[(t0 + i) & 7] + dstoff);
    } else {
        for (int k = 1; k <= 22; ++k) {
            int tau = t0 + k;
            const char* src = (tau < T_DIM) ? (xb + bbase + (size_t)tau * SLAB_B) : (const char*)zpage;
            glds16(src + srcoff, (char*)Bsl[tau % 24] + dstoff);
        }
    }
    asm volatile("s_waitcnt vmcnt(0)" ::: "memory");
    __builtin_amdgcn_s_barrier();
    asm volatile("" ::: "memory");
    if (wvalid) {
#pragma unroll
        for (int j = 1; j <= 9; ++j) {
            int tau = t0 + 20 - 10 * h - j;          // slot = tau%10 = 10-j
            const char* sb = (const char*)Bsl[tau % 24];
            ring[10 - j][0] = *(const bf16x8*)(sb + boff0);
            ring[10 - j][1] = *(const bf16x8*)(sb + boff1);
        }
    }

    // ---- main loop: 80 steps (8 x unroll-10), depth-3 prefetch ----
    for (int tb = t0; tb < t1; tb += 10) {
#pragma unroll
        for (int u = 0; u < 10; ++u) {
            int t = tb + u;
            if (isA) {
                int tn = t + 3;
                const char* src = (tn < T_DIM) ? (xb + abase + (size_t)tn * SLAB_B) : (const char*)zpage;
                glds16(src + srcoff, (char*)Asl[tn & 7] + dstoff);
            } else {
                int tau = t + 23;
                const char* src = (tau < T_DIM) ? (xb + bbase + (size_t)tau * SLAB_B) : (const char*)zpage;
                glds16(src + srcoff, (char*)Bsl[tau % 24] + dstoff);
            }
            asm volatile("s_waitcnt vmcnt(3)" ::: "memory");   // step-t slabs ready
            __builtin_amdgcn_s_barrier();
            asm volatile("" ::: "memory");
            if (wvalid) {
                const char* sa = (const char*)Asl[t & 7];
                bf16x8 a0 = *(const bf16x8*)(sa + aoff0);
                bf16x8 a1 = *(const bf16x8*)(sa + aoff1);
                int tauf = t + 20 - 10 * h;
                const char* sb = (const char*)Bsl[tauf % 24];
                ring[u][0] = *(const bf16x8*)(sb + boff0);
                ring[u][1] = *(const bf16x8*)(sb + boff1);
#pragma unroll
                for (int j = 0; j < 10; ++j) {
                    acc[j] = __builtin_amdgcn_mfma_f32_16x16x32_bf16(a0, ring[(u - j + 10) % 10][0], acc[j], 0, 0, 0);
                    acc[j] = __builtin_amdgcn_mfma_f32_16x16x32_bf16(a1, ring[(u - j + 10) % 10][1], acc[j], 0, 0, 0);
                }
            }
        }
    }

    // ---- store: wave's 10 shifts, s = 10h+1+j ----
    int col = mf * 16 + fr;
    if (col < L_DIM) {
        float* pbase = part + (size_t)(split * B_DIM + b) * J_TOT * L_DIM;
#pragma unroll
        for (int j = 0; j < 10; ++j) {
            int s = 10 * h + 1 + j;
#pragma unroll
            for (int r = 0; r < 4; ++r) {
                int row = lf * 16 + kg * 4 + r;
                if (row < L_DIM)
                    pbase[((size_t)s * L_DIM + row) * L_DIM + col] = acc[j][r];
            }
        }
    }
}

// ---------------- K1b: s=0 only (p=287, 33 t-steps) — proven path -----------
__global__ void __launch_bounds__(256) k_sim0(const unsigned short* __restrict__ xbf,
                                              float* __restrict__ part) {
    __shared__ __align__(16) unsigned short S[2][2][8192];   // 64 KB

    int id = blockIdx.x;
    int tile = id & 3;
    int rest = id >> 2;
    int split = rest & 3;
    int b = rest >> 2;
    int l0 = (tile >> 1) * 128, m0 = (tile & 1) * 128;

    const int p = 287;
    int nt = T_DIM - p;                  // 33
    int t0 = (split * nt) >> 2;
    int t1 = (((split + 1) * nt) >> 2);

    int tid = threadIdx.x;
    int wave = tid >> 6, lane = tid & 63;
    int wl = wave >> 1, wm = wave & 1;
    int fr = lane & 15, kg = lane >> 4;
    int x7 = fr & 7;

    int rN = 0, cN = 0;
#pragma unroll
    for (int g = 0; g < 4; ++g) {
        if (l0 + (g * 2 + wl) * 16 < L_DIM) rN = g + 1;
        if (m0 + (g * 2 + wm) * 16 < L_DIM) cN = g + 1;
    }

    int srcoff[4];
#pragma unroll
    for (int i = 0; i < 4; ++i) {
        int n = i * 256 + wave * 64 + lane;
        int row = n >> 3, c = n & 7;
        srcoff[i] = row * 128 + ((c ^ (row & 7)) * 16);
    }
    int wbase = wave * 1024;

    int cb0 = (kg ^ x7) * 16, cb1 = ((4 + kg) ^ x7) * 16;
    int aro[4], bro[4];
#pragma unroll
    for (int g = 0; g < 4; ++g) {
        aro[g] = ((g * 2 + wl) * 16 + fr) * 128;
        bro[g] = ((g * 2 + wm) * 16 + fr) * 128;
    }

    f32x4 acc[4][4];
#pragma unroll
    for (int i = 0; i < 4; ++i)
#pragma unroll
        for (int j = 0; j < 4; ++j) acc[i][j] = f32x4{0.f, 0.f, 0.f, 0.f};

    const size_t LDB = (size_t)LD_ROW * 2;
    const char* abase = (const char*)xbf + ((size_t)b * T_DIM * LD_ROW + (size_t)l0 * 64) * 2;
    const char* bbase = (const char*)xbf + ((size_t)(b * T_DIM + p) * LD_ROW + (size_t)m0 * 64) * 2;

    if (t1 > t0) {
        {
            const char* a = abase + (size_t)t0 * LDB;
            const char* bb = bbase + (size_t)t0 * LDB;
            char* lA = (char*)&S[0][0][0] + wbase;
            char* lB = (char*)&S[0][1][0] + wbase;
#pragma unroll
            for (int i = 0; i < 4; ++i) {
                glds16(a + srcoff[i], lA + i * 4096);
                glds16(bb + srcoff[i], lB + i * 4096);
            }
        }
        int cur = 0;
        for (int t = t0; t < t1; ++t) {
            bool more = (t + 1 < t1);
            if (more) {
                const char* a = abase + (size_t)(t + 1) * LDB;
                const char* bb = bbase + (size_t)(t + 1) * LDB;
                char* lA = (char*)&S[cur ^ 1][0][0] + wbase;
                char* lB = (char*)&S[cur ^ 1][1][0] + wbase;
#pragma unroll
                for (int i = 0; i < 4; ++i) {
                    glds16(a + srcoff[i], lA + i * 4096);
                    glds16(bb + srcoff[i], lB + i * 4096);
                }
                asm volatile("s_waitcnt vmcnt(8)" ::: "memory");
            } else {
                asm volatile("s_waitcnt vmcnt(0)" ::: "memory");
            }
            __builtin_amdgcn_s_barrier();
            asm volatile("" ::: "memory");
            const char* lA = (const char*)&S[cur][0][0];
            const char* lB = (const char*)&S[cur][1][0];
#pragma unroll
            for (int kd = 0; kd < 2; ++kd) {
                int cb = kd ? cb1 : cb0;
                bf16x8 af[4], bv[4];
#pragma unroll
                for (int g = 0; g < 4; ++g)
                    if (g < rN) af[g] = *(const bf16x8*)(lA + aro[g] + cb);
#pragma unroll
                for (int g = 0; g < 4; ++g)
                    if (g < cN) bv[g] = *(const bf16x8*)(lB + bro[g] + cb);
#pragma unroll
                for (int rg = 0; rg < 4; ++rg)
                    if (rg < rN)
#pragma unroll
                        for (int cg = 0; cg < 4; ++cg)
                            if (cg < cN)
                                acc[rg][cg] = __builtin_amdgcn_mfma_f32_16x16x32_bf16(
                                    af[rg], bv[cg], acc[rg][cg], 0, 0, 0);
            }
            asm volatile("" ::: "memory");
            __builtin_amdgcn_s_barrier();
            cur ^= 1;
        }
    }

    float* pdst = part + ((size_t)(split * B_DIM + b) * J_TOT + (size_t)0 * L_DIM) * L_DIM;
#pragma unroll
    for (int rg = 0; rg < 4; ++rg)
#pragma unroll
        for (int cg = 0; cg < 4; ++cg) {
            int col = m0 + (cg * 2 + wm) * 16 + fr;
            if (col < L_DIM) {
#pragma unroll
                for (int r = 0; r < 4; ++r) {
                    int row = l0 + (rg * 2 + wl) * 16 + kg * 4 + r;
                    if (row < L_DIM) pdst[(size_t)row * L_DIM + col] = acc[rg][cg][r];
                }
            }
        }
}

// K2: partial sum of exp over j-chunks. grid (NCH_A=128, B), block 256.
__global__ void __launch_bounds__(256) k_sumexp(const float* __restrict__ part,
                                                const float* __restrict__ w,
                                                float* __restrict__ psum) {
    int c = blockIdx.x, b = blockIdx.y;
    int m = threadIdx.x;
    if (m >= L_DIM) return;
    float scale = w[0] / (float)T_DIM;
    int j0 = c * CH_A, j1 = imin(j0 + CH_A, J_TOT);
    float acc = 0.0f;
    for (int j = j0; j < j1; ++j) {
        float v = 0.0f;
#pragma unroll
        for (int r = 0; r < NSPLIT; ++r)
            v += part[((size_t)(r * B_DIM + b) * J_TOT + j) * L_DIM + m];
        acc += __expf(v * scale);
    }
    psum[(b * NCH_A + c) * L_DIM + m] = acc;
}

// K3: pack probs to bf16 pp[b][s][mc][i(256)][mi]. grid (NCH_P, B), block 256.
__global__ void __launch_bounds__(256) k_pack(const float* __restrict__ part,
                                              const float* __restrict__ w,
                                              const float* __restrict__ psum,
                                              unsigned short* __restrict__ pp) {
    __shared__ float sinv[L_DIM];
    int c = blockIdx.x, b = blockIdx.y;
    int tid = threadIdx.x;
    if (tid < L_DIM) {
        float g = 0.0f;
        for (int q = 0; q < NCH_A; ++q) g += psum[(b * NCH_A + q) * L_DIM + tid];
        sinv[tid] = 1.0f / g;
    }
    __syncthreads();
    if (tid >= MPAD) return;
    float scale = w[0] / (float)T_DIM;
    float inv = (tid < L_DIM) ? sinv[tid] : 0.0f;
    int mc = tid >> 5, mi = tid & 31;
    int j0 = c * CH_P, j1 = imin(j0 + CH_P, J_TOT);
    for (int j = j0; j < j1; ++j) {
        float pr = 0.0f;
        if (tid < L_DIM) {
            float v = 0.0f;
#pragma unroll
            for (int r = 0; r < NSPLIT; ++r)
                v += part[((size_t)(r * B_DIM + b) * J_TOT + j) * L_DIM + tid];
            pr = __expf(v * scale) * inv;
        }
        int i = j / S_DIM, s = j % S_DIM;
        pp[((((size_t)b * S_DIM + s) * 7 + mc) * IPAD + i) * 32 + mi] = f2bf(pr);
    }
}

// ---------------- K4: out = P @ x_shift --------------------------------------
// v5: flat chunk index q = k*7+mc, 4 LDS buffers (64 KB), 2-deep prefetch
// (stage q+2, vmcnt(8) counted, never 0 mid-loop), ONE barrier per chunk
// (ring distance 3 >= max wave skew 1). Grid flat 640, XCD swizzle in low 3.
__global__ void __launch_bounds__(256) k_out(const unsigned short* __restrict__ ppn,
                                             const unsigned short* __restrict__ xtn,
                                             float* __restrict__ out) {
    __shared__ __align__(16) unsigned short As[4][128 * 32];     // 4 x 8 KB
    __shared__ __align__(16) unsigned short Bs[4][2][64 * 32];   // 4 x 8 KB

    int id = blockIdx.x;
    int low = id & 7;
    int b = low >> 2, tr = low & 3;
    int rest = id >> 3;
    int tg = rest >> 1;
    int ih = rest & 1;
    int t0 = tr * TSPLIT + tg * 2;
    int i0 = ih * 128;

    int tid = threadIdx.x;
    int wave = tid >> 6, lane = tid & 63;
    int wt = wave >> 1, wi = wave & 1;
    int fr = lane & 15, kg = lane >> 4;
    int t = t0 + wt;

    const char* ppb = (const char*)ppn + (size_t)b * (S_DIM * 7 * IPAD * 32) * 2;
    const char* xtb = (const char*)xtn + (size_t)b * (T_DIM * 7 * 64 * 32) * 2;

    int asrc[2], bsrc[2];
#pragma unroll
    for (int i = 0; i < 2; ++i) {
        int n = wave * 128 + i * 64 + lane;
        int row = n >> 2, c = n & 3;
        asrc[i] = row * 64 + ((c ^ ((row >> 1) & 3)) * 16);
        int n2 = (wave & 1) * 128 + i * 64 + lane;
        int row2 = n2 >> 2, c2 = n2 & 3;
        bsrc[i] = row2 * 64 + ((c2 ^ ((row2 >> 1) & 3)) * 16);
    }
    int btau = wave >> 1;

    int cb = (kg ^ ((fr >> 1) & 3)) * 16;
    int aro[4], bro[4];
#pragma unroll
    for (int g = 0; g < 4; ++g) {
        aro[g] = (wi * 64 + g * 16 + fr) * 64;
        bro[g] = (g * 16 + fr) * 64;
    }

    f32x4 acc[4][4];
#pragma unroll
    for (int i = 0; i < 4; ++i)
#pragma unroll
        for (int j = 0; j < 4; ++j) acc[i][j] = f32x4{0.f, 0.f, 0.f, 0.f};

    int has0 = (t0 <= 32) ? 1 : 0;
    int sBegin = imax(1, t0 - 298);
    int ns = (21 - sBegin) + has0;
    int Q = ns * 7;

    auto sOf = [&](int k) { return (has0 && k == 0) ? 0 : sBegin + (k - has0); };

    auto stage = [&](int q, int buf) {
        int ss = sOf(q / 7), mc = q % 7;
        const char* ga = ppb + (((size_t)(ss * 7 + mc) * IPAD + i0) * 32) * 2;
        char* lA = (char*)&As[buf][0] + wave * 2048;
        glds16(ga + asrc[0], lA);
        glds16(ga + asrc[1], lA + 1024);
        int pp_ = shift_p(ss);
        int tau = imin(t0 + btau + pp_, T_DIM - 1);
        const char* gb = xtb + ((size_t)tau * 7 + mc) * 4096;
        char* lB = (char*)&Bs[buf][btau][0] + (wave & 1) * 2048;
        glds16(gb + bsrc[0], lB);
        glds16(gb + bsrc[1], lB + 1024);
    };

    stage(0, 0);
    stage(1, 1);
    for (int q = 0; q < Q; ++q) {
        if (q + 2 < Q) {
            stage(q + 2, (q + 2) & 3);
            asm volatile("s_waitcnt vmcnt(8)" ::: "memory");   // chunk q's 4 done
        } else if (q + 1 < Q) {
            asm volatile("s_waitcnt vmcnt(4)" ::: "memory");
        } else {
            asm volatile("s_waitcnt vmcnt(0)" ::: "memory");
        }
        __builtin_amdgcn_s_barrier();
        asm volatile("" ::: "memory");
        int sc = sOf(q / 7);
        int p = shift_p(sc);
        if (t + p < T_DIM) {             // wave-uniform
            const char* lA = (const char*)&As[q & 3][0];
            const char* lB = (const char*)&Bs[q & 3][wt][0];
            bf16x8 af[4], bv[4];
#pragma unroll
            for (int g = 0; g < 4; ++g) af[g] = *(const bf16x8*)(lA + aro[g] + cb);
#pragma unroll
            for (int g = 0; g < 4; ++g) bv[g] = *(const bf16x8*)(lB + bro[g] + cb);
#pragma unroll
            for (int rg = 0; rg < 4; ++rg)
#pragma unroll
                for (int cg = 0; cg < 4; ++cg)
                    acc[rg][cg] = __builtin_amdgcn_mfma_f32_16x16x32_bf16(
                        af[rg], bv[cg], acc[rg][cg], 0, 0, 0);
        }
        asm volatile("" ::: "memory");
    }

    float* obase = out + (size_t)(b * T_DIM + t) * LD_ROW;
#pragma unroll
    for (int rg = 0; rg < 4; ++rg)
#pragma unroll
        for (int cg = 0; cg < 4; ++cg) {
            int d = cg * 16 + fr;
#pragma unroll
            for (int r = 0; r < 4; ++r) {
                int i = i0 + wi * 64 + rg * 16 + kg * 4 + r;
                if (i < L_DIM) obase[(size_t)i * D_DIM + d] = acc[rg][cg][r];
            }
        }
}

extern "C" void kernel_launch(void* const* d_in, const int* in_sizes, int n_in,
                              void* d_out, int out_size, void* d_ws, size_t ws_size,
                              hipStream_t stream) {
    const float* x = (const float*)d_in[0];
    const float* w = (const float*)d_in[1];
    float* out = (float*)d_out;

    char* ws = (char*)d_ws;
    size_t off = 0;
    auto carve = [&](size_t bytes) {
        void* p = ws + off;
        off += (bytes + 255) & ~(size_t)255;
        return p;
    };
    unsigned short* xbf = (unsigned short*)carve((size_t)B_DIM * T_DIM * LD_ROW * 2);          // 17.0 MB
    unsigned short* xt  = (unsigned short*)carve((size_t)B_DIM * T_DIM * 7 * 64 * 32 * 2);     // 18.4 MB
    float* part         = (float*)carve((size_t)NSPLIT * B_DIM * J_TOT * L_DIM * 4);           // 28.8 MB
    float* psum         = (float*)carve((size_t)B_DIM * NCH_A * L_DIM * 4);                    // 212 KB
    size_t pp_bytes = (size_t)B_DIM * S_DIM * 7 * IPAD * 32 * 2;                               // 4.8 MB
    unsigned short* pp  = (unsigned short*)carve(pp_bytes);
    unsigned short* zpage = (unsigned short*)carve(4096);                                      // zero page

    k_prep<<<B_DIM * T_DIM, 256, 0, stream>>>(x, xbf, xt);
    hipMemsetAsync(zpage, 0, 4096, stream);
    k_simr<<<NSPLIT * 98, 512, 0, stream>>>(xbf, zpage, part);
    k_sim0<<<B_DIM * NSPLIT * 4, 256, 0, stream>>>(xbf, part);
    k_sumexp<<<dim3(NCH_A, B_DIM), 256, 0, stream>>>(part, w, psum);
    hipMemsetAsync(pp, 0, pp_bytes, stream);   // zero pad rows (i >= 207)
    k_pack<<<dim3(NCH_P, B_DIM), 256, 0, stream>>>(part, w, psum, pp);
    k_out<<<640, 256, 0, stream>>>(pp, xt, out);
}

// Round 6
// 320.038 us; speedup vs baseline: 1.2479x; 1.2479x over previous
//
#include <hip/hip_runtime.h>
#include <hip/hip_bf16.h>

#define B_DIM 2
#define T_DIM 320
#define L_DIM 207
#define D_DIM 64
#define S_DIM 21
#define J_TOT (S_DIM * L_DIM)   // 4347
#define MPAD 224                // m padded to 7*32
#define IPAD 256                // i padded for pp chunks
#define NSPLIT 4
#define TSPLIT 80               // 320/4
#define NCH_A 128
#define CH_A 34                 // ceil(4347/128)
#define NCH_P 128
#define CH_P 34                 // ceil(4347/128)
#define LD_ROW (L_DIM * D_DIM)  // 13248
#define SLAB_B 26496            // bytes per (b,t) slab of xbf

typedef __attribute__((ext_vector_type(8))) short bf16x8;   // 8 bf16 (4 VGPRs)
typedef __attribute__((ext_vector_type(4))) float f32x4;

__device__ inline unsigned short f2bf(float f) {
    unsigned int u = __builtin_bit_cast(unsigned int, f);
    u = (u + 0x7FFFu + ((u >> 16) & 1u)) >> 16;   // RNE
    return (unsigned short)u;
}

__device__ inline int shift_p(int s) { return (s == 0) ? 287 : (21 - s); }
__device__ inline int imin(int a, int b) { return a < b ? a : b; }
__device__ inline int imax(int a, int b) { return a > b ? a : b; }

// async 16B global->LDS (DMA). LDS dest = wave-uniform base + lane*16;
// global source is per-lane.
__device__ __forceinline__ void glds16(const void* g, void* l) {
    __builtin_amdgcn_global_load_lds(
        (const __attribute__((address_space(1))) void*)g,
        (__attribute__((address_space(3))) void*)l,
        16, 0, 0);
}

// K0: x fp32 [B,T,L,D] -> xbf bf16 [B,T,L,D] and xt bf16 [B,T][mc7][d64][mi32]
__global__ void __launch_bounds__(256) k_prep(const float* __restrict__ x,
                                              unsigned short* __restrict__ xbf,
                                              unsigned short* __restrict__ xt) {
    __shared__ float tile[L_DIM * 66];
    int bt = blockIdx.x;
    const float* src = x + (size_t)bt * LD_ROW;
    int tid = threadIdx.x;
    for (int idx = tid; idx < L_DIM * D_DIM; idx += 256) {
        int l = idx >> 6, d = idx & 63;
        tile[l * 66 + d] = src[idx];
    }
    __syncthreads();
    unsigned short* dst1 = xbf + (size_t)bt * LD_ROW;
    for (int idx = tid; idx < L_DIM * D_DIM; idx += 256) {
        int l = idx >> 6, d = idx & 63;
        dst1[idx] = f2bf(tile[l * 66 + d]);
    }
    unsigned short* dst2 = xt + (size_t)bt * (7 * 64 * 32);
    if (tid < MPAD) {
        int mc = tid >> 5, mi = tid & 31;
        for (int d = 0; d < D_DIM; ++d) {
            float v = (tid < L_DIM) ? tile[tid * 66 + d] : 0.0f;
            dst2[(mc * 64 + d) * 32 + mi] = f2bf(v);
        }
    }
}

// ---------------- K1a: logit partials for s=1..20 (register-ring) -----------
// v5 (kept): prefetch depth 3 (vmcnt(3)); A-ring 8 slabs, B-ring 24 slabs.
// One barrier/step. LDS 128 KB -> 1 block/CU, 512 threads.
__global__ void __launch_bounds__(512, 2) k_simr(const unsigned short* __restrict__ xbf,
                                                 const unsigned short* __restrict__ zpage,
                                                 float* __restrict__ part) {
    __shared__ __align__(16) unsigned short Asl[8][2048];    // 8 x 4 KB
    __shared__ __align__(16) unsigned short Bsl[24][2048];   // 24 x 4 KB

    int id = blockIdx.x;
    int split = id / 98;                 // 0..3 (t-chunk)
    int r2 = id % 98;
    int b = r2 & 1;
    int pb = r2 >> 1;                    // 0..48
    int lfb = pb / 7, mfb = pb % 7;

    int t0 = split * TSPLIT;             // 0,80,160,240 (== 0 mod 10)
    int t1 = t0 + TSPLIT;

    int tid = threadIdx.x;
    int w = tid >> 6, lane = tid & 63;
    int wl = w & 1, wm = (w >> 1) & 1, h = w >> 2;
    int fr = lane & 15, kg = lane >> 4;
    int x7 = fr & 7;

    int lf = lfb * 2 + wl;               // 0..13
    int mf = mfb * 2 + wm;
    bool wvalid = (lf <= 12) && (mf <= 12);   // frag 13 is pure pad

    // staging: waves 0-3 stage A-slab (4 KB), waves 4-7 stage B-slab.
    bool isA = (w < 4);
    int gq = (w & 3) * 64 + lane;        // 0..255 within stage group
    int grow = gq >> 3, gc = gq & 7;
    int srcoff = grow * 128 + ((gc ^ (grow & 7)) * 16);   // pre-swizzled source
    int dstoff = (w & 3) * 1024;         // wave-uniform LDS dest base

    const char* xb = (const char*)xbf;
    size_t abase = (size_t)b * T_DIM * SLAB_B + lfb * 4096;
    size_t bbase = (size_t)b * T_DIM * SLAB_B + mfb * 4096;

    // fragment read offsets (read-side XOR matches source pre-swizzle)
    int lrA = wl * 16 + fr, lrB = wm * 16 + fr;
    int c0 = ((0 + kg) ^ x7) * 16, c1 = ((4 + kg) ^ x7) * 16;
    int aoff0 = lrA * 128 + c0, aoff1 = lrA * 128 + c1;
    int boff0 = lrB * 128 + c0, boff1 = lrB * 128 + c1;

    f32x4 acc[10];
#pragma unroll
    for (int j = 0; j < 10; ++j) acc[j] = f32x4{0.f, 0.f, 0.f, 0.f};
    bf16x8 ring[10][2];                  // ALL indices compile-time (rule 20)

    // ---- prologue: stage A(t0..t0+2) + B(t0+1..t0+22), drain, preload ring
    if (isA) {
#pragma unroll
        for (int i = 0; i < 3; ++i)
            glds16(xb + abase + (size_t)(t0 + i) * SLAB_B + srcoff,
                   (char*)Asl[(t0 + i) & 7] + dstoff);
    } else {
        for (int k = 1; k <= 22; ++k) {
            int tau = t0 + k;
            const char* src = (tau < T_DIM) ? (xb + bbase + (size_t)tau * SLAB_B) : (const char*)zpage;
            glds16(src + srcoff, (char*)Bsl[tau % 24] + dstoff);
        }
    }
    asm volatile("s_waitcnt vmcnt(0)" ::: "memory");
    __builtin_amdgcn_s_barrier();
    asm volatile("" ::: "memory");
    if (wvalid) {
#pragma unroll
        for (int j = 1; j <= 9; ++j) {
            int tau = t0 + 20 - 10 * h - j;          // slot = tau%10 = 10-j
            const char* sb = (const char*)Bsl[tau % 24];
            ring[10 - j][0] = *(const bf16x8*)(sb + boff0);
            ring[10 - j][1] = *(const bf16x8*)(sb + boff1);
        }
    }

    // ---- main loop: 80 steps (8 x unroll-10), depth-3 prefetch ----
    for (int tb = t0; tb < t1; tb += 10) {
#pragma unroll
        for (int u = 0; u < 10; ++u) {
            int t = tb + u;
            if (isA) {
                int tn = t + 3;
                const char* src = (tn < T_DIM) ? (xb + abase + (size_t)tn * SLAB_B) : (const char*)zpage;
                glds16(src + srcoff, (char*)Asl[tn & 7] + dstoff);
            } else {
                int tau = t + 23;
                const char* src = (tau < T_DIM) ? (xb + bbase + (size_t)tau * SLAB_B) : (const char*)zpage;
                glds16(src + srcoff, (char*)Bsl[tau % 24] + dstoff);
            }
            asm volatile("s_waitcnt vmcnt(3)" ::: "memory");   // step-t slabs ready
            __builtin_amdgcn_s_barrier();
            asm volatile("" ::: "memory");
            if (wvalid) {
                const char* sa = (const char*)Asl[t & 7];
                bf16x8 a0 = *(const bf16x8*)(sa + aoff0);
                bf16x8 a1 = *(const bf16x8*)(sa + aoff1);
                int tauf = t + 20 - 10 * h;
                const char* sb = (const char*)Bsl[tauf % 24];
                ring[u][0] = *(const bf16x8*)(sb + boff0);
                ring[u][1] = *(const bf16x8*)(sb + boff1);
#pragma unroll
                for (int j = 0; j < 10; ++j) {
                    acc[j] = __builtin_amdgcn_mfma_f32_16x16x32_bf16(a0, ring[(u - j + 10) % 10][0], acc[j], 0, 0, 0);
                    acc[j] = __builtin_amdgcn_mfma_f32_16x16x32_bf16(a1, ring[(u - j + 10) % 10][1], acc[j], 0, 0, 0);
                }
            }
        }
    }

    // ---- store: wave's 10 shifts, s = 10h+1+j ----
    int col = mf * 16 + fr;
    if (col < L_DIM) {
        float* pbase = part + (size_t)(split * B_DIM + b) * J_TOT * L_DIM;
#pragma unroll
        for (int j = 0; j < 10; ++j) {
            int s = 10 * h + 1 + j;
#pragma unroll
            for (int r = 0; r < 4; ++r) {
                int row = lf * 16 + kg * 4 + r;
                if (row < L_DIM)
                    pbase[((size_t)s * L_DIM + row) * L_DIM + col] = acc[j][r];
            }
        }
    }
}

// ---------------- K1b: s=0 only (p=287, 33 t-steps) — proven path -----------
__global__ void __launch_bounds__(256) k_sim0(const unsigned short* __restrict__ xbf,
                                              float* __restrict__ part) {
    __shared__ __align__(16) unsigned short S[2][2][8192];   // 64 KB

    int id = blockIdx.x;
    int tile = id & 3;
    int rest = id >> 2;
    int split = rest & 3;
    int b = rest >> 2;
    int l0 = (tile >> 1) * 128, m0 = (tile & 1) * 128;

    const int p = 287;
    int nt = T_DIM - p;                  // 33
    int t0 = (split * nt) >> 2;
    int t1 = (((split + 1) * nt) >> 2);

    int tid = threadIdx.x;
    int wave = tid >> 6, lane = tid & 63;
    int wl = wave >> 1, wm = wave & 1;
    int fr = lane & 15, kg = lane >> 4;
    int x7 = fr & 7;

    int rN = 0, cN = 0;
#pragma unroll
    for (int g = 0; g < 4; ++g) {
        if (l0 + (g * 2 + wl) * 16 < L_DIM) rN = g + 1;
        if (m0 + (g * 2 + wm) * 16 < L_DIM) cN = g + 1;
    }

    int srcoff[4];
#pragma unroll
    for (int i = 0; i < 4; ++i) {
        int n = i * 256 + wave * 64 + lane;
        int row = n >> 3, c = n & 7;
        srcoff[i] = row * 128 + ((c ^ (row & 7)) * 16);
    }
    int wbase = wave * 1024;

    int cb0 = (kg ^ x7) * 16, cb1 = ((4 + kg) ^ x7) * 16;
    int aro[4], bro[4];
#pragma unroll
    for (int g = 0; g < 4; ++g) {
        aro[g] = ((g * 2 + wl) * 16 + fr) * 128;
        bro[g] = ((g * 2 + wm) * 16 + fr) * 128;
    }

    f32x4 acc[4][4];
#pragma unroll
    for (int i = 0; i < 4; ++i)
#pragma unroll
        for (int j = 0; j < 4; ++j) acc[i][j] = f32x4{0.f, 0.f, 0.f, 0.f};

    const size_t LDB = (size_t)LD_ROW * 2;
    const char* abase = (const char*)xbf + ((size_t)b * T_DIM * LD_ROW + (size_t)l0 * 64) * 2;
    const char* bbase = (const char*)xbf + ((size_t)(b * T_DIM + p) * LD_ROW + (size_t)m0 * 64) * 2;

    if (t1 > t0) {
        {
            const char* a = abase + (size_t)t0 * LDB;
            const char* bb = bbase + (size_t)t0 * LDB;
            char* lA = (char*)&S[0][0][0] + wbase;
            char* lB = (char*)&S[0][1][0] + wbase;
#pragma unroll
            for (int i = 0; i < 4; ++i) {
                glds16(a + srcoff[i], lA + i * 4096);
                glds16(bb + srcoff[i], lB + i * 4096);
            }
        }
        int cur = 0;
        for (int t = t0; t < t1; ++t) {
            bool more = (t + 1 < t1);
            if (more) {
                const char* a = abase + (size_t)(t + 1) * LDB;
                const char* bb = bbase + (size_t)(t + 1) * LDB;
                char* lA = (char*)&S[cur ^ 1][0][0] + wbase;
                char* lB = (char*)&S[cur ^ 1][1][0] + wbase;
#pragma unroll
                for (int i = 0; i < 4; ++i) {
                    glds16(a + srcoff[i], lA + i * 4096);
                    glds16(bb + srcoff[i], lB + i * 4096);
                }
                asm volatile("s_waitcnt vmcnt(8)" ::: "memory");
            } else {
                asm volatile("s_waitcnt vmcnt(0)" ::: "memory");
            }
            __builtin_amdgcn_s_barrier();
            asm volatile("" ::: "memory");
            const char* lA = (const char*)&S[cur][0][0];
            const char* lB = (const char*)&S[cur][1][0];
#pragma unroll
            for (int kd = 0; kd < 2; ++kd) {
                int cb = kd ? cb1 : cb0;
                bf16x8 af[4], bv[4];
#pragma unroll
                for (int g = 0; g < 4; ++g)
                    if (g < rN) af[g] = *(const bf16x8*)(lA + aro[g] + cb);
#pragma unroll
                for (int g = 0; g < 4; ++g)
                    if (g < cN) bv[g] = *(const bf16x8*)(lB + bro[g] + cb);
#pragma unroll
                for (int rg = 0; rg < 4; ++rg)
                    if (rg < rN)
#pragma unroll
                        for (int cg = 0; cg < 4; ++cg)
                            if (cg < cN)
                                acc[rg][cg] = __builtin_amdgcn_mfma_f32_16x16x32_bf16(
                                    af[rg], bv[cg], acc[rg][cg], 0, 0, 0);
            }
            asm volatile("" ::: "memory");
            __builtin_amdgcn_s_barrier();
            cur ^= 1;
        }
    }

    float* pdst = part + ((size_t)(split * B_DIM + b) * J_TOT + (size_t)0 * L_DIM) * L_DIM;
#pragma unroll
    for (int rg = 0; rg < 4; ++rg)
#pragma unroll
        for (int cg = 0; cg < 4; ++cg) {
            int col = m0 + (cg * 2 + wm) * 16 + fr;
            if (col < L_DIM) {
#pragma unroll
                for (int r = 0; r < 4; ++r) {
                    int row = l0 + (rg * 2 + wl) * 16 + kg * 4 + r;
                    if (row < L_DIM) pdst[(size_t)row * L_DIM + col] = acc[rg][cg][r];
                }
            }
        }
}

// K2: partial sum of exp over j-chunks. grid (NCH_A=128, B), block 256.
__global__ void __launch_bounds__(256) k_sumexp(const float* __restrict__ part,
                                                const float* __restrict__ w,
                                                float* __restrict__ psum) {
    int c = blockIdx.x, b = blockIdx.y;
    int m = threadIdx.x;
    if (m >= L_DIM) return;
    float scale = w[0] / (float)T_DIM;
    int j0 = c * CH_A, j1 = imin(j0 + CH_A, J_TOT);
    float acc = 0.0f;
    for (int j = j0; j < j1; ++j) {
        float v = 0.0f;
#pragma unroll
        for (int r = 0; r < NSPLIT; ++r)
            v += part[((size_t)(r * B_DIM + b) * J_TOT + j) * L_DIM + m];
        acc += __expf(v * scale);
    }
    psum[(b * NCH_A + c) * L_DIM + m] = acc;
}

// K3: pack probs to bf16 pp[b][s][mc][i(256)][mi]. grid (NCH_P, B), block 256.
__global__ void __launch_bounds__(256) k_pack(const float* __restrict__ part,
                                              const float* __restrict__ w,
                                              const float* __restrict__ psum,
                                              unsigned short* __restrict__ pp) {
    __shared__ float sinv[L_DIM];
    int c = blockIdx.x, b = blockIdx.y;
    int tid = threadIdx.x;
    if (tid < L_DIM) {
        float g = 0.0f;
        for (int q = 0; q < NCH_A; ++q) g += psum[(b * NCH_A + q) * L_DIM + tid];
        sinv[tid] = 1.0f / g;
    }
    __syncthreads();
    if (tid >= MPAD) return;
    float scale = w[0] / (float)T_DIM;
    float inv = (tid < L_DIM) ? sinv[tid] : 0.0f;
    int mc = tid >> 5, mi = tid & 31;
    int j0 = c * CH_P, j1 = imin(j0 + CH_P, J_TOT);
    for (int j = j0; j < j1; ++j) {
        float pr = 0.0f;
        if (tid < L_DIM) {
            float v = 0.0f;
#pragma unroll
            for (int r = 0; r < NSPLIT; ++r)
                v += part[((size_t)(r * B_DIM + b) * J_TOT + j) * L_DIM + tid];
            pr = __expf(v * scale) * inv;
        }
        int i = j / S_DIM, s = j % S_DIM;
        pp[((((size_t)b * S_DIM + s) * 7 + mc) * IPAD + i) * 32 + mi] = f2bf(pr);
    }
}

// ---------------- K4: out = P @ x_shift (round-3/4 proven version) ----------
// 2 LDS buffers (32 KB), 2 barriers/chunk, counted vmcnt(4). 72 VGPR,
// ~2.5 blocks/CU grid-limited occupancy. Measured 104 us @ MfmaUtil 37%.
__global__ void __launch_bounds__(256) k_out(const unsigned short* __restrict__ ppn,
                                             const unsigned short* __restrict__ xtn,
                                             float* __restrict__ out) {
    __shared__ __align__(16) unsigned short As[2][128 * 32];
    __shared__ __align__(16) unsigned short Bs[2][2][64 * 32];

    int id = blockIdx.x;
    int low = id & 7;
    int b = low >> 2, tr = low & 3;
    int rest = id >> 3;
    int tg = rest >> 1;
    int ih = rest & 1;
    int t0 = tr * TSPLIT + tg * 2;
    int i0 = ih * 128;

    int tid = threadIdx.x;
    int wave = tid >> 6, lane = tid & 63;
    int wt = wave >> 1, wi = wave & 1;
    int fr = lane & 15, kg = lane >> 4;
    int t = t0 + wt;

    const char* ppb = (const char*)ppn + (size_t)b * (S_DIM * 7 * IPAD * 32) * 2;
    const char* xtb = (const char*)xtn + (size_t)b * (T_DIM * 7 * 64 * 32) * 2;

    int asrc[2], bsrc[2];
#pragma unroll
    for (int i = 0; i < 2; ++i) {
        int n = wave * 128 + i * 64 + lane;
        int row = n >> 2, c = n & 3;
        asrc[i] = row * 64 + ((c ^ ((row >> 1) & 3)) * 16);
        int n2 = (wave & 1) * 128 + i * 64 + lane;
        int row2 = n2 >> 2, c2 = n2 & 3;
        bsrc[i] = row2 * 64 + ((c2 ^ ((row2 >> 1) & 3)) * 16);
    }
    int btau = wave >> 1;

    int cb = (kg ^ ((fr >> 1) & 3)) * 16;
    int aro[4], bro[4];
#pragma unroll
    for (int g = 0; g < 4; ++g) {
        aro[g] = (wi * 64 + g * 16 + fr) * 64;
        bro[g] = (g * 16 + fr) * 64;
    }

    f32x4 acc[4][4];
#pragma unroll
    for (int i = 0; i < 4; ++i)
#pragma unroll
        for (int j = 0; j < 4; ++j) acc[i][j] = f32x4{0.f, 0.f, 0.f, 0.f};

    int has0 = (t0 <= 32) ? 1 : 0;
    int sBegin = imax(1, t0 - 298);
    int ns = (21 - sBegin) + has0;

    auto sOf = [&](int k) { return (has0 && k == 0) ? 0 : sBegin + (k - has0); };

    auto stage = [&](int ss, int mc, int buf) {
        const char* ga = ppb + (((size_t)(ss * 7 + mc) * IPAD + i0) * 32) * 2;
        char* lA = (char*)&As[buf][0] + wave * 2048;
        glds16(ga + asrc[0], lA);
        glds16(ga + asrc[1], lA + 1024);
        int pp_ = shift_p(ss);
        int tau = imin(t0 + btau + pp_, T_DIM - 1);
        const char* gb = xtb + ((size_t)tau * 7 + mc) * 4096;
        char* lB = (char*)&Bs[buf][btau][0] + (wave & 1) * 2048;
        glds16(gb + bsrc[0], lB);
        glds16(gb + bsrc[1], lB + 1024);
    };

    stage(sOf(0), 0, 0);
    int cur = 0;
    for (int k = 0; k < ns; ++k) {
        int s = sOf(k);
        int p = shift_p(s);
        bool valid = (t + p < T_DIM);
        for (int mc = 0; mc < 7; ++mc) {
            bool more = (mc < 6) || (k + 1 < ns);
            if (more) {
                int s2 = (mc < 6) ? s : sOf(k + 1);
                int mc2 = (mc < 6) ? mc + 1 : 0;
                stage(s2, mc2, cur ^ 1);
                asm volatile("s_waitcnt vmcnt(4)" ::: "memory");
            } else {
                asm volatile("s_waitcnt vmcnt(0)" ::: "memory");
            }
            __builtin_amdgcn_s_barrier();
            asm volatile("" ::: "memory");
            if (valid) {
                const char* lA = (const char*)&As[cur][0];
                const char* lB = (const char*)&Bs[cur][wt][0];
                bf16x8 af[4], bv[4];
#pragma unroll
                for (int g = 0; g < 4; ++g) af[g] = *(const bf16x8*)(lA + aro[g] + cb);
#pragma unroll
                for (int g = 0; g < 4; ++g) bv[g] = *(const bf16x8*)(lB + bro[g] + cb);
#pragma unroll
                for (int rg = 0; rg < 4; ++rg)
#pragma unroll
                    for (int cg = 0; cg < 4; ++cg)
                        acc[rg][cg] = __builtin_amdgcn_mfma_f32_16x16x32_bf16(
                            af[rg], bv[cg], acc[rg][cg], 0, 0, 0);
            }
            asm volatile("" ::: "memory");
            __builtin_amdgcn_s_barrier();
            cur ^= 1;
        }
    }

    float* obase = out + (size_t)(b * T_DIM + t) * LD_ROW;
#pragma unroll
    for (int rg = 0; rg < 4; ++rg)
#pragma unroll
        for (int cg = 0; cg < 4; ++cg) {
            int d = cg * 16 + fr;
#pragma unroll
            for (int r = 0; r < 4; ++r) {
                int i = i0 + wi * 64 + rg * 16 + kg * 4 + r;
                if (i < L_DIM) obase[(size_t)i * D_DIM + d] = acc[rg][cg][r];
            }
        }
}

extern "C" void kernel_launch(void* const* d_in, const int* in_sizes, int n_in,
                              void* d_out, int out_size, void* d_ws, size_t ws_size,
                              hipStream_t stream) {
    const float* x = (const float*)d_in[0];
    const float* w = (const float*)d_in[1];
    float* out = (float*)d_out;

    char* ws = (char*)d_ws;
    size_t off = 0;
    auto carve = [&](size_t bytes) {
        void* p = ws + off;
        off += (bytes + 255) & ~(size_t)255;
        return p;
    };
    unsigned short* xbf = (unsigned short*)carve((size_t)B_DIM * T_DIM * LD_ROW * 2);          // 17.0 MB
    unsigned short* xt  = (unsigned short*)carve((size_t)B_DIM * T_DIM * 7 * 64 * 32 * 2);     // 18.4 MB
    float* part         = (float*)carve((size_t)NSPLIT * B_DIM * J_TOT * L_DIM * 4);           // 28.8 MB
    float* psum         = (float*)carve((size_t)B_DIM * NCH_A * L_DIM * 4);                    // 212 KB
    size_t pp_bytes = (size_t)B_DIM * S_DIM * 7 * IPAD * 32 * 2;                               // 4.8 MB
    unsigned short* pp  = (unsigned short*)carve(pp_bytes);
    unsigned short* zpage = (unsigned short*)carve(4096);                                      // zero page

    k_prep<<<B_DIM * T_DIM, 256, 0, stream>>>(x, xbf, xt);
    hipMemsetAsync(zpage, 0, 4096, stream);
    k_simr<<<NSPLIT * 98, 512, 0, stream>>>(xbf, zpage, part);
    k_sim0<<<B_DIM * NSPLIT * 4, 256, 0, stream>>>(xbf, part);
    k_sumexp<<<dim3(NCH_A, B_DIM), 256, 0, stream>>>(part, w, psum);
    hipMemsetAsync(pp, 0, pp_bytes, stream);   // zero pad rows (i >= 207)
    k_pack<<<dim3(NCH_P, B_DIM), 256, 0, stream>>>(part, w, psum, pp);
    k_out<<<640, 256, 0, stream>>>(pp, xt, out);
}